// Round 3
// baseline (707.206 us; speedup 1.0000x reference)
//
#include <hip/hip_runtime.h>
#include <math.h>

// MoE router: logits = x[16384,2048] @ W^T[2048,64]; softmax; top-2; renorm.
// Compute-bound on the fp32 vector ALU (no fp32 MFMA): 4.3 GFLOP/157TF = 27.4us.
//
// R2 post-mortem: streaming W through the scalar pipe (s_load) thrashes the
// K$ and serializes on mixed lgkmcnt waits -> 228us. R3 delivers BOTH
// operands from LDS with known costs:
//   per-FMA delivery = 8/E (per-lane x b128) + c_b/T (broadcast W b128)
//   -> T=4 tokens/lane, E=16 experts/wave puts LDS at ~0.7 of VALU capacity.
// Wave = 256 tok x 16 e; block = 512 tok x 64 e (8 waves = 4 egroups x 2
// token-halves) over a 256-k slice; grid = 32 token-tiles x 8 K-splits = 256
// blocks (1/CU, 2 waves/SIMD). Partial logits (32MB) -> d_ws; kernel2 reduces
// 8 partials + softmax + top-2.
// LDS: 16-k tiles, row stride 20 dwords -> b128 reads/writes provably
// conflict-free ((20r)%32 spreads starts 4 apart); x 40KB + W 5KB = 45KB.

#define NTOK   16384
#define DDIM   2048
#define NE     64
#define TT     512     // tokens per block
#define KS     8       // K splits (grid dim)
#define KRANGE 256     // 2048/8
#define KTILE  16
#define NTILE  16      // KRANGE/KTILE
#define XSTR   20      // LDS row stride in dwords (16 k + 4 pad, 16B-aligned)

__global__ __launch_bounds__(512, 2) void router_gemm(
    const float* __restrict__ x, const float* __restrict__ W,
    float* __restrict__ pws)
{
    __shared__ __align__(16) float xs[TT * XSTR];   // 40 KB
    __shared__ __align__(16) float wsm[NE * XSTR];  //  5 KB

    const int tid  = threadIdx.x;
    const int lane = tid & 63;
    const int wv   = __builtin_amdgcn_readfirstlane(tid >> 6);
    const int eg   = wv & 3;    // expert group: e in [16*eg, 16*eg+16)
    const int th   = wv >> 2;   // token half: 256 tokens
    const int bx   = blockIdx.x;
    const int ks   = bx & 7;    // K-split; same-ks blocks share the W slice
    const int tt   = bx >> 3;   // token tile
    const int tok0 = tt * TT;
    const int kb   = ks * KRANGE;

    // ---- staging maps (x: 2048 float4/tile, 4/thread; W: 256 float4) ----
    const float* xg[4]; int xl[4];
#pragma unroll
    for (int i = 0; i < 4; ++i) {
        const int f = tid + 512 * i;          // 0..2047
        const int r = f >> 2, c4 = f & 3;     // 4 threads/row -> 64B chunks
        xg[i] = x + (size_t)(tok0 + r) * DDIM + kb + 4 * c4;
        xl[i] = r * XSTR + 4 * c4;
    }
    const float* wg = nullptr; int wl = 0;
    if (tid < 256) {
        const int e = tid >> 2, c4 = tid & 3;
        wg = W + (size_t)e * DDIM + kb + 4 * c4;
        wl = e * XSTR + 4 * c4;
    }

    // ---- prologue: stage tile 0 ----
    float4 px[4], pw;
#pragma unroll
    for (int i = 0; i < 4; ++i) px[i] = *(const float4*)xg[i];
    if (tid < 256) pw = *(const float4*)wg;
#pragma unroll
    for (int i = 0; i < 4; ++i) *(float4*)&xs[xl[i]] = px[i];
    if (tid < 256) *(float4*)&wsm[wl] = pw;
    __syncthreads();

    float acc[16][4];   // [expert][token-slot] = 64 VGPR
#pragma unroll
    for (int j = 0; j < 16; ++j)
#pragma unroll
        for (int c = 0; c < 4; ++c) acc[j][c] = 0.f;

    const int xoff = (th * 256 + lane) * XSTR;
    const int woff = eg * 16 * XSTR;

#pragma unroll 1
    for (int t = 0; t < NTILE; ++t) {
        // prefetch tile t+1 into regs; latency hides under 1024 FMAs
        if (t + 1 < NTILE) {
            const int ko = (t + 1) * KTILE;
#pragma unroll
            for (int i = 0; i < 4; ++i) px[i] = *(const float4*)(xg[i] + ko);
            if (tid < 256) pw = *(const float4*)(wg + ko);
        }
#pragma unroll
        for (int kk = 0; kk < KTILE; kk += 4) {
            float4 xf[4];
#pragma unroll
            for (int c = 0; c < 4; ++c)
                xf[c] = *(const float4*)&xs[xoff + c * 64 * XSTR + kk];
#pragma unroll
            for (int j = 0; j < 16; ++j) {
                const float4 w4 = *(const float4*)&wsm[woff + j * XSTR + kk];
#pragma unroll
                for (int c = 0; c < 4; ++c) {
                    acc[j][c] = fmaf(xf[c].x, w4.x, acc[j][c]);
                    acc[j][c] = fmaf(xf[c].y, w4.y, acc[j][c]);
                    acc[j][c] = fmaf(xf[c].z, w4.z, acc[j][c]);
                    acc[j][c] = fmaf(xf[c].w, w4.w, acc[j][c]);
                }
            }
        }
        __syncthreads();          // everyone done reading tile t
        if (t + 1 < NTILE) {
#pragma unroll
            for (int i = 0; i < 4; ++i) *(float4*)&xs[xl[i]] = px[i];
            if (tid < 256) *(float4*)&wsm[wl] = pw;
        }
        __syncthreads();          // tile t+1 visible
    }

    // ---- write partial logits: pws[ks][token][e] ----
#pragma unroll
    for (int c = 0; c < 4; ++c) {
        const int tok = tok0 + th * 256 + c * 64 + lane;
        float* p = pws + ((size_t)ks * NTOK + tok) * NE + eg * 16;
#pragma unroll
        for (int g = 0; g < 4; ++g) {
            float4 o;
            o.x = acc[4 * g + 0][c];
            o.y = acc[4 * g + 1][c];
            o.z = acc[4 * g + 2][c];
            o.w = acc[4 * g + 3][c];
            *(float4*)(p + 4 * g) = o;
        }
    }
}

// reduce 8 K-split partials, softmax, top-2, renorm, write all outputs
__global__ __launch_bounds__(64) void router_fix(
    const float* __restrict__ pws, float* __restrict__ out)
{
    const int t = blockIdx.x * 64 + threadIdx.x;   // token
    float p[NE];
#pragma unroll
    for (int e = 0; e < NE; ++e) p[e] = 0.f;
#pragma unroll 1
    for (int ks = 0; ks < KS; ++ks) {
        const float4* q = (const float4*)(pws + ((size_t)ks * NTOK + t) * NE);
#pragma unroll
        for (int j = 0; j < 16; ++j) {
            const float4 v = q[j];
            p[4 * j + 0] += v.x;
            p[4 * j + 1] += v.y;
            p[4 * j + 2] += v.z;
            p[4 * j + 3] += v.w;
        }
    }

    float m = p[0];
#pragma unroll
    for (int e = 1; e < NE; ++e) m = fmaxf(m, p[e]);
    float s = 0.f;
#pragma unroll
    for (int e = 0; e < NE; ++e) { p[e] = expf(p[e] - m); s += p[e]; }
    const float inv = 1.f / s;

    // top-2 on exp-values (same order as probs); lax.top_k tie-break =
    // lowest index first -> strict '>' ascending scan
    float v1 = -1.f; int i1 = 0;
#pragma unroll
    for (int e = 0; e < NE; ++e) { if (p[e] > v1) { v1 = p[e]; i1 = e; } }
    float v2 = -1.f; int i2 = 0;
#pragma unroll
    for (int e = 0; e < NE; ++e) { if (e != i1 && p[e] > v2) { v2 = p[e]; i2 = e; } }

    const float ts = v1 + v2;
    float* out_tp = out;              // top_k_probs  [NTOK][2]
    float* out_ti = out + 2 * NTOK;   // top_k_indices[NTOK][2] (float values)
    float* out_p  = out + 4 * NTOK;   // probs        [NTOK][NE]

    out_tp[t * 2 + 0] = v1 / ts;
    out_tp[t * 2 + 1] = v2 / ts;
    out_ti[t * 2 + 0] = (float)i1;
    out_ti[t * 2 + 1] = (float)i2;

    float* po = out_p + (size_t)t * NE;
#pragma unroll
    for (int j = 0; j < 16; ++j) {
        float4 v = make_float4(p[4 * j + 0] * inv, p[4 * j + 1] * inv,
                               p[4 * j + 2] * inv, p[4 * j + 3] * inv);
        *(float4*)(po + 4 * j) = v;
    }
}

extern "C" void kernel_launch(void* const* d_in, const int* in_sizes, int n_in,
                              void* d_out, int out_size, void* d_ws, size_t ws_size,
                              hipStream_t stream) {
    const float* x = (const float*)d_in[0];
    const float* W = (const float*)d_in[1];
    float* out     = (float*)d_out;
    float* pws     = (float*)d_ws;    // needs KS*NTOK*NE*4 = 32 MB scratch

    router_gemm<<<dim3((NTOK / TT) * KS), dim3(512), 0, stream>>>(x, W, pws);
    router_fix<<<dim3(NTOK / 64), dim3(64), 0, stream>>>(pws, out);
}